// Round 7
// baseline (539.317 us; speedup 1.0000x reference)
//
#include <hip/hip_runtime.h>

#define NRES 512
#define N2   262144   // 512*512

typedef __attribute__((ext_vector_type(8))) short s16x8;
typedef __attribute__((ext_vector_type(4))) float f32x4;

__device__ __forceinline__ ushort f2bf(float x){
  union { float f; unsigned u; } v; v.f = x;
  unsigned r = (v.u + 0x7FFFu + ((v.u >> 16) & 1u)) >> 16;
  return (ushort)r;
}
__device__ __forceinline__ float bf2f(ushort h){
  union { unsigned u; float f; } v; v.u = ((unsigned)h) << 16; return v.f;
}
__device__ __forceinline__ unsigned pkbf(float lo, float hi){
  unsigned r;
  asm volatile("v_cvt_pk_bf16_f32 %0, %1, %2" : "=v"(r) : "v"(lo), "v"(hi));
  return r;
}
__device__ __forceinline__ float sigm(float x){ return 1.0f / (1.0f + __expf(-x)); }

__device__ __forceinline__ void gld_lds16(const void* g, void* lds){
  __builtin_amdgcn_global_load_lds((const __attribute__((address_space(1))) void*)g,
                                   (__attribute__((address_space(3))) void*)lds, 16, 0, 0);
}

#define VMCNT(n) asm volatile("s_waitcnt vmcnt(" #n ")" ::: "memory")

// -------------------- kernel 0: weight transpose+convert --------------------
__global__ void k0_prep(const float* __restrict__ lp, const float* __restrict__ lg,
                        const float* __restrict__ rp, const float* __restrict__ rg,
                        const float* __restrict__ gw, const float* __restrict__ ow,
                        ushort* __restrict__ Wt)
{
  const float* srcs[6] = {lp, lg, rp, rg, gw, ow};
  const float* wsrc = srcs[blockIdx.x];
  ushort* dst = Wt + blockIdx.x * 16384;
  for (int f = threadIdx.x; f < 16384; f += blockDim.x){
    int n = f >> 7, k = f & 127;
    dst[f] = f2bf(wsrc[k * 128 + n]);
  }
}

// -------------------- kernel 1a: input layernorm -> bf16 a_ln ---------------
__global__ __launch_bounds__(256) void k1a_ln(
    const float* __restrict__ act, const float* __restrict__ ln_g,
    const float* __restrict__ ln_b, ushort* __restrict__ a_ln)
{
  const int t = threadIdx.x;
  const int p0 = blockIdx.x * 128;
  const int g = t >> 5, j = t & 31;
  const float4 gv = *(const float4*)(ln_g + j * 4);
  const float4 bv = *(const float4*)(ln_b + j * 4);
  #pragma unroll
  for (int i = 0; i < 16; ++i){
    const int row = p0 + g + (i << 3);
    float4 v = *(const float4*)(act + (size_t)row * 128 + j * 4);
    float s = v.x + v.y + v.z + v.w;
    float q = v.x*v.x + v.y*v.y + v.z*v.z + v.w*v.w;
    #pragma unroll
    for (int m = 1; m < 32; m <<= 1){ s += __shfl_xor(s, m); q += __shfl_xor(q, m); }
    float mu = s * (1.0f / 128.0f);
    float rs = rsqrtf(q * (1.0f / 128.0f) - mu * mu + 1e-5f);
    uint2 o;
    o.x = pkbf((v.x - mu) * rs * gv.x + bv.x, (v.y - mu) * rs * gv.y + bv.y);
    o.y = pkbf((v.z - mu) * rs * gv.z + bv.z, (v.w - mu) * rs * gv.w + bv.w);
    *(uint2*)(a_ln + (size_t)row * 128 + j * 4) = o;
  }
}

// -------------------- kernel 1b: 5 projections, no-LDS-A GEMM ---------------
// 4 waves; slab = w*6+i in [0,24): out = slab>>3 (left/right/gate),
// c0 = (slab&7)*16. A-frags direct from global a_ln (L3-hot), weight frags
// transient per slab (L2-hot). Stores via per-wave LDS transpose.
__global__ __launch_bounds__(256) void k1b_proj(
    const ushort* __restrict__ a_ln, const float* __restrict__ mask,
    const float* __restrict__ lp_b, const float* __restrict__ lg_b,
    const float* __restrict__ rp_b, const float* __restrict__ rg_b,
    const float* __restrict__ gate_b, const ushort* __restrict__ Wt,
    ushort* __restrict__ leftg, ushort* __restrict__ rightg,
    ushort* __restrict__ gateg)
{
  __shared__ ushort Scr[4][16 * 72];   // per-wave transpose scratch, 9216 B
  const int t = threadIdx.x;
  const int p0 = blockIdx.x * 128;
  const int lane = t & 63, w = t >> 6;
  const int cl = lane & 15, h = lane >> 4;
  const float* Pb[3] = {lp_b, rp_b, gate_b};
  const float* Gb[2] = {lg_b, rg_b};
  ushort* dsts[3] = {leftg, rightg, gateg};
  ushort* scr = &Scr[w][0];
  const int rc = lane >> 2, rq = lane & 3;
  const f32x4 z = {0.f, 0.f, 0.f, 0.f};

  #pragma unroll
  for (int mh = 0; mh < 2; ++mh){
    // A-fragments for rows [mh*64, +64), direct from global (bf16, L3-hot)
    s16x8 a[4][4];
    #pragma unroll
    for (int m = 0; m < 4; ++m)
      #pragma unroll
      for (int ks = 0; ks < 4; ++ks)
        a[m][ks] = *(const s16x8*)(a_ln + (size_t)(p0 + mh*64 + m*16 + cl) * 128
                                        + ks*32 + h*8);
    float mk[4][4];
    #pragma unroll
    for (int m = 0; m < 4; ++m)
      #pragma unroll
      for (int r = 0; r < 4; ++r)
        mk[m][r] = mask[p0 + mh*64 + m*16 + h*4 + r];

    for (int i = 0; i < 6; ++i){
      const int slab = w * 6 + i;
      const int out = slab >> 3;
      const int c0 = (slab & 7) << 4;
      const bool hasG = (out < 2);
      const ushort* WPp = Wt + (size_t)(out * 2) * 16384 + (size_t)(c0 + cl) * 128;
      s16x8 wfP[4], wfG[4];
      #pragma unroll
      for (int ks = 0; ks < 4; ++ks)
        wfP[ks] = *(const s16x8*)(WPp + ks*32 + h*8);
      if (hasG)
        #pragma unroll
        for (int ks = 0; ks < 4; ++ks)
          wfG[ks] = *(const s16x8*)(WPp + 16384 + ks*32 + h*8);
      const float pb = Pb[out][c0 + cl];
      const float gb = hasG ? Gb[out][c0 + cl] : 0.f;

      f32x4 accP[4], accG[4];
      #pragma unroll
      for (int m = 0; m < 4; ++m){ accP[m] = z; accG[m] = z; }
      #pragma unroll
      for (int ks = 0; ks < 4; ++ks)
        #pragma unroll
        for (int m = 0; m < 4; ++m)
          accP[m] = __builtin_amdgcn_mfma_f32_16x16x32_bf16(a[m][ks], wfP[ks], accP[m], 0, 0, 0);
      if (hasG){
        #pragma unroll
        for (int ks = 0; ks < 4; ++ks)
          #pragma unroll
          for (int m = 0; m < 4; ++m)
            accG[m] = __builtin_amdgcn_mfma_f32_16x16x32_bf16(a[m][ks], wfG[ks], accG[m], 0, 0, 0);
      }

      uint2 o[4];
      if (hasG){
        #pragma unroll
        for (int m = 0; m < 4; ++m){
          float x0 = mk[m][0] * (accP[m][0] + pb) * sigm(accG[m][0] + gb);
          float x1 = mk[m][1] * (accP[m][1] + pb) * sigm(accG[m][1] + gb);
          float x2 = mk[m][2] * (accP[m][2] + pb) * sigm(accG[m][2] + gb);
          float x3 = mk[m][3] * (accP[m][3] + pb) * sigm(accG[m][3] + gb);
          o[m].x = pkbf(x0, x1); o[m].y = pkbf(x2, x3);
        }
      } else {
        #pragma unroll
        for (int m = 0; m < 4; ++m){
          o[m].x = pkbf(sigm(accP[m][0] + pb), sigm(accP[m][1] + pb));
          o[m].y = pkbf(sigm(accP[m][2] + pb), sigm(accP[m][3] + pb));
        }
      }
      // per-wave transpose -> full-line channel-major stores
      #pragma unroll
      for (int m = 0; m < 4; ++m)
        *(uint2*)&scr[cl * 72 + m * 16 + h * 4] = o[m];
      asm volatile("s_waitcnt lgkmcnt(0)" ::: "memory");
      ushort* dstg = dsts[out] + (size_t)c0 * N2 + p0 + mh * 64;
      s16x8 r0 = *(const s16x8*)&scr[rc * 72 + rq * 16];
      s16x8 r1 = *(const s16x8*)&scr[rc * 72 + rq * 16 + 8];
      *(s16x8*)(dstg + (size_t)rc * N2 + rq * 16)     = r0;
      *(s16x8*)(dstg + (size_t)rc * N2 + rq * 16 + 8) = r1;
    }
  }
}

// -------------------- kernel 2: per-channel NT GEMM (triangle) --------------
// depth-2 counted-vmcnt pipeline (3 buffers), 2-way-free XOR swizzle.
__global__ __launch_bounds__(256) void k2_tri(const ushort* __restrict__ leftg,
                                              const ushort* __restrict__ rightg,
                                              ushort* __restrict__ X)
{
  __shared__ ushort Ab[3][128 * 32];
  __shared__ ushort Bb[3][128 * 32];
  const int t = threadIdx.x, lane = t & 63, w = t >> 6;
  const int b = blockIdx.x;
  const int c = b & 127, tile = b >> 7;
  const int tm = (tile >> 2) * 128, tn = (tile & 3) * 128;
  const char* Lc = (const char*)(leftg  + (size_t)c * N2);
  const char* Rc = (const char*)(rightg + (size_t)c * N2);
  ushort* Xc = X + (size_t)c * N2;
  const int wr = w >> 1, wc = w & 1, cl = lane & 15, h = lane >> 4;

  const int o0 = (w    ) * 1024 + lane * 16;
  const int o1 = (w + 4) * 1024 + lane * 16;
  const int row0 = o0 >> 6, row1 = o1 >> 6;
  const int sk0 = ((((o0 >> 4) & 3) ^ ((row0 >> 1) & 3)) << 4);
  const int sk1 = ((((o1 >> 4) & 3) ^ ((row1 >> 1) & 3)) << 4);

  f32x4 acc[4][4];
  const f32x4 z = {0.f, 0.f, 0.f, 0.f};
  #pragma unroll
  for (int m = 0; m < 4; ++m)
    #pragma unroll
    for (int n = 0; n < 4; ++n) acc[m][n] = z;

  auto stage = [&](int buf, int kt){
    gld_lds16(Lc + (size_t)(tm + row0) * 1024 + kt * 64 + sk0, (char*)&Ab[buf][0] + o0);
    gld_lds16(Lc + (size_t)(tm + row1) * 1024 + kt * 64 + sk1, (char*)&Ab[buf][0] + o1);
    gld_lds16(Rc + (size_t)(tn + row0) * 1024 + kt * 64 + sk0, (char*)&Bb[buf][0] + o0);
    gld_lds16(Rc + (size_t)(tn + row1) * 1024 + kt * 64 + sk1, (char*)&Bb[buf][0] + o1);
  };
  const int rsw = ((h ^ ((cl >> 1) & 3)) << 4);
  auto compute = [&](int buf){
    s16x8 a2[4], b2[4];
    #pragma unroll
    for (int m = 0; m < 4; ++m)
      a2[m] = *(const s16x8*)((const char*)&Ab[buf][0] + (wr*64 + m*16 + cl) * 64 + rsw);
    #pragma unroll
    for (int n = 0; n < 4; ++n)
      b2[n] = *(const s16x8*)((const char*)&Bb[buf][0] + (wc*64 + n*16 + cl) * 64 + rsw);
    #pragma unroll
    for (int m = 0; m < 4; ++m)
      #pragma unroll
      for (int n = 0; n < 4; ++n)
        acc[m][n] = __builtin_amdgcn_mfma_f32_16x16x32_bf16(a2[m], b2[n], acc[m][n], 0, 0, 0);
  };

  stage(0, 0);
  stage(1, 1);
  int cur = 0;
  for (int kt = 0; kt < 14; ++kt){
    VMCNT(4);                              // tile kt landed; kt+1 stays in flight
    __builtin_amdgcn_s_barrier();
    __builtin_amdgcn_sched_barrier(0);
    compute(cur);
    int nb = cur + 2; if (nb >= 3) nb -= 3;
    stage(nb, kt + 2);                     // issue tile kt+2, no drain
    cur = (cur == 2) ? 0 : cur + 1;
  }
  VMCNT(4);                                // kt=14
  __builtin_amdgcn_s_barrier();
  __builtin_amdgcn_sched_barrier(0);
  compute(cur);
  cur = (cur == 2) ? 0 : cur + 1;
  VMCNT(0);                                // kt=15
  __builtin_amdgcn_s_barrier();
  __builtin_amdgcn_sched_barrier(0);
  compute(cur);

  #pragma unroll
  for (int m = 0; m < 4; ++m)
    #pragma unroll
    for (int n = 0; n < 4; ++n)
      #pragma unroll
      for (int r = 0; r < 4; ++r)
        Xc[(size_t)(tm + wr*64 + m*16 + h*4 + r) * NRES + tn + wc*64 + n*16 + cl] =
            f2bf(acc[m][n][r]);
}

// -------------------- kernel 3: LN + out projection * gate ------------------
__global__ __launch_bounds__(256) void k3_out(
    const ushort* __restrict__ X, const ushort* __restrict__ gateg,
    const ushort* __restrict__ Wt5,
    const float* __restrict__ ln_g, const float* __restrict__ ln_b,
    const float* __restrict__ ob, float* __restrict__ out)
{
  __shared__ ushort Alds[128 * 136];
  __shared__ ushort Wlds[128 * 136];
  __shared__ float part[8][2][128];
  __shared__ float stat[2][128];
  const int t = threadIdx.x;
  const int p0 = blockIdx.x * 128;
  const int g = t >> 5, j = t & 31;

  float4 xv[16];
  float s0 = 0, s1 = 0, s2 = 0, s3 = 0, q0 = 0, q1 = 0, q2 = 0, q3 = 0;
  #pragma unroll
  for (int i = 0; i < 16; ++i){
    const int cch = g + (i << 3);
    ushort4 u4 = *(const ushort4*)(X + (size_t)cch * N2 + p0 + j * 4);
    xv[i].x = bf2f(u4.x); xv[i].y = bf2f(u4.y);
    xv[i].z = bf2f(u4.z); xv[i].w = bf2f(u4.w);
    s0 += xv[i].x; q0 += xv[i].x * xv[i].x;
    s1 += xv[i].y; q1 += xv[i].y * xv[i].y;
    s2 += xv[i].z; q2 += xv[i].z * xv[i].z;
    s3 += xv[i].w; q3 += xv[i].w * xv[i].w;
  }
  part[g][0][j*4+0] = s0; part[g][0][j*4+1] = s1;
  part[g][0][j*4+2] = s2; part[g][0][j*4+3] = s3;
  part[g][1][j*4+0] = q0; part[g][1][j*4+1] = q1;
  part[g][1][j*4+2] = q2; part[g][1][j*4+3] = q3;
  __syncthreads();
  if (t < 128){
    float s = 0, q = 0;
    #pragma unroll
    for (int gg = 0; gg < 8; ++gg){ s += part[gg][0][t]; q += part[gg][1][t]; }
    float mu = s * (1.0f / 128.0f);
    float rs = rsqrtf(q * (1.0f / 128.0f) - mu * mu + 1e-5f);
    stat[0][t] = mu; stat[1][t] = rs;
  }
  __syncthreads();
  #pragma unroll
  for (int i = 0; i < 16; ++i){
    const int cch = g + (i << 3);
    const float gc = ln_g[cch], bc = ln_b[cch];
    const int p = j * 4;
    Alds[(p+0) * 136 + cch] = f2bf((xv[i].x - stat[0][p+0]) * stat[1][p+0] * gc + bc);
    Alds[(p+1) * 136 + cch] = f2bf((xv[i].y - stat[0][p+1]) * stat[1][p+1] * gc + bc);
    Alds[(p+2) * 136 + cch] = f2bf((xv[i].z - stat[0][p+2]) * stat[1][p+2] * gc + bc);
    Alds[(p+3) * 136 + cch] = f2bf((xv[i].w - stat[0][p+3]) * stat[1][p+3] * gc + bc);
  }
  #pragma unroll
  for (int u = 0; u < 8; ++u){
    int f = t + u * 256;
    int n = f >> 4, k8 = f & 15;
    *(s16x8*)&Wlds[n * 136 + k8 * 8] = *(const s16x8*)(Wt5 + f * 8);
  }
  __syncthreads();

  const int lane = t & 63, w = t >> 6;
  const int wr = w >> 1, wc = w & 1, cl = lane & 15, h = lane >> 4;
  f32x4 acc[4][4];
  const f32x4 z = {0.f, 0.f, 0.f, 0.f};
  #pragma unroll
  for (int m = 0; m < 4; ++m)
    #pragma unroll
    for (int n = 0; n < 4; ++n) acc[m][n] = z;
  #pragma unroll
  for (int ks = 0; ks < 4; ++ks){
    s16x8 a[4], bfr[4];
    #pragma unroll
    for (int m = 0; m < 4; ++m)
      a[m] = *(const s16x8*)&Alds[(wr*64 + m*16 + cl) * 136 + ks*32 + h*8];
    #pragma unroll
    for (int n = 0; n < 4; ++n)
      bfr[n] = *(const s16x8*)&Wlds[(wc*64 + n*16 + cl) * 136 + ks*32 + h*8];
    #pragma unroll
    for (int m = 0; m < 4; ++m)
      #pragma unroll
      for (int n = 0; n < 4; ++n)
        acc[m][n] = __builtin_amdgcn_mfma_f32_16x16x32_bf16(a[m], bfr[n], acc[m][n], 0, 0, 0);
  }

  float obv[4];
  #pragma unroll
  for (int n = 0; n < 4; ++n) obv[n] = ob[wc*64 + n*16 + cl];
  #pragma unroll
  for (int m = 0; m < 4; ++m)
    #pragma unroll
    for (int n = 0; n < 4; ++n){
      const int cc = wc*64 + n*16 + cl;
      ushort4 g4 = *(const ushort4*)(gateg + (size_t)cc * N2 + p0 + wr*64 + m*16 + h*4);
      const size_t pbase = p0 + wr*64 + m*16 + h*4;
      out[(pbase+0) * 128 + cc] = (acc[m][n][0] + obv[n]) * bf2f(g4.x);
      out[(pbase+1) * 128 + cc] = (acc[m][n][1] + obv[n]) * bf2f(g4.y);
      out[(pbase+2) * 128 + cc] = (acc[m][n][2] + obv[n]) * bf2f(g4.z);
      out[(pbase+3) * 128 + cc] = (acc[m][n][3] + obv[n]) * bf2f(g4.w);
    }
}

// -------------------- launcher ----------------------------------------------
extern "C" void kernel_launch(void* const* d_in, const int* in_sizes, int n_in,
                              void* d_out, int out_size, void* d_ws, size_t ws_size,
                              hipStream_t stream)
{
  const float* act    = (const float*)d_in[0];
  const float* mask   = (const float*)d_in[1];
  const float* ln_in_g = (const float*)d_in[2];
  const float* ln_in_b = (const float*)d_in[3];
  const float* lp_w = (const float*)d_in[4];
  const float* lp_b = (const float*)d_in[5];
  const float* rp_w = (const float*)d_in[6];
  const float* rp_b = (const float*)d_in[7];
  const float* lg_w = (const float*)d_in[8];
  const float* lg_b = (const float*)d_in[9];
  const float* rg_w = (const float*)d_in[10];
  const float* rg_b = (const float*)d_in[11];
  const float* ln_c_g = (const float*)d_in[12];
  const float* ln_c_b = (const float*)d_in[13];
  const float* out_w  = (const float*)d_in[14];
  const float* out_b  = (const float*)d_in[15];
  const float* gate_w = (const float*)d_in[16];
  const float* gate_b = (const float*)d_in[17];
  float* outp = (float*)d_out;

  char* ws = (char*)d_ws;
  ushort* Wt     = (ushort*)(ws);                                  // 196608 B
  ushort* a_ln   = (ushort*)(ws + 196608);                         // 64 MB
  ushort* leftg  = (ushort*)(ws + 196608 + 1ull * 67108864ull);    // 64 MB
  ushort* rightg = (ushort*)(ws + 196608 + 2ull * 67108864ull);    // 64 MB
  ushort* gateg  = (ushort*)(ws + 196608 + 3ull * 67108864ull);    // 64 MB
  ushort* X      = (ushort*)(ws + 196608 + 4ull * 67108864ull);    // 64 MB

  k0_prep<<<dim3(6), dim3(256), 0, stream>>>(lp_w, lg_w, rp_w, rg_w, gate_w, out_w, Wt);
  k1a_ln<<<dim3(2048), dim3(256), 0, stream>>>(act, ln_in_g, ln_in_b, a_ln);
  k1b_proj<<<dim3(2048), dim3(256), 0, stream>>>(a_ln, mask,
                                                 lp_b, lg_b, rp_b, rg_b, gate_b,
                                                 Wt, leftg, rightg, gateg);
  k2_tri<<<dim3(2048), dim3(256), 0, stream>>>(leftg, rightg, X);
  k3_out<<<dim3(2048), dim3(256), 0, stream>>>(X, gateg, Wt + 5 * 16384,
                                               ln_c_g, ln_c_b, out_b, outp);
}